// Round 13
// baseline (41.166 us; speedup 1.0000x reference)
//
#include <hip/hip_runtime.h>

#define FDIM 512
#define CDIM 64
#define NLEAF 1024
#define MAT (FDIM * CDIM)          /* 32768 floats per node */
#define OUT_LOGITS (NLEAF * CDIM)  /* 65536 */

__device__ __forceinline__ float abs4(const float4 v) {
    return fabsf(v.x) + fabsf(v.y) + fabsf(v.z) + fabsf(v.w);
}
__device__ __forceinline__ float sq4(const float4 v) {
    return v.x * v.x + v.y * v.y + v.z * v.z + v.w * v.w;
}

// Shared-ancestor stream: this thread's 16f x 4c tile of one node,
// 4 bursts x 4-deep (R3/R11-proven shape); FMA into BOTH leaves' accs.
// MODE: 0 = none, 1 = L1*scale, 2 = squared (root)   [verbatim from R11]
template<int MODE>
__device__ __forceinline__ void stream2(const float* __restrict__ dbase,
                                        const float4 xr[2][4],
                                        float4* __restrict__ acc,
                                        float& rsum, float s)
{
#pragma unroll
    for (int h = 0; h < 4; ++h) {
        const float* q = dbase + (size_t)(4 * h) * CDIM;
        const float4 d0 = *(const float4*)(q);
        const float4 d1 = *(const float4*)(q + CDIM);
        const float4 d2 = *(const float4*)(q + 2 * CDIM);
        const float4 d3 = *(const float4*)(q + 3 * CDIM);
        if (MODE == 1) rsum = fmaf(abs4(d0) + abs4(d1) + abs4(d2) + abs4(d3), s, rsum);
        if (MODE == 2) rsum += sq4(d0) + sq4(d1) + sq4(d2) + sq4(d3);
#pragma unroll
        for (int r = 0; r < 2; ++r) {
            const float4 xv = xr[r][h];
            acc[r].x += xv.x * d0.x + xv.y * d1.x + xv.z * d2.x + xv.w * d3.x;
            acc[r].y += xv.x * d0.y + xv.y * d1.y + xv.z * d2.y + xv.w * d3.y;
            acc[r].z += xv.x * d0.z + xv.y * d1.z + xv.z * d2.z + xv.w * d3.z;
            acc[r].w += xv.x * d0.w + xv.y * d1.w + xv.z * d2.w + xv.w * d3.w;
        }
    }
}

// Leaf stream: same shape, FMA into acc[R] only; always reg-owner. [R11]
template<int R>
__device__ __forceinline__ void stream1(const float* __restrict__ dbase,
                                        const float4 xr[2][4],
                                        float4* __restrict__ acc,
                                        float& rsum, float s)
{
#pragma unroll
    for (int h = 0; h < 4; ++h) {
        const float* q = dbase + (size_t)(4 * h) * CDIM;
        const float4 d0 = *(const float4*)(q);
        const float4 d1 = *(const float4*)(q + CDIM);
        const float4 d2 = *(const float4*)(q + 2 * CDIM);
        const float4 d3 = *(const float4*)(q + 3 * CDIM);
        rsum = fmaf(abs4(d0) + abs4(d1) + abs4(d2) + abs4(d3), s, rsum);
        const float4 xv = xr[R][h];
        acc[R].x += xv.x * d0.x + xv.y * d1.x + xv.z * d2.x + xv.w * d3.x;
        acc[R].y += xv.x * d0.y + xv.y * d1.y + xv.z * d2.y + xv.w * d3.y;
        acc[R].z += xv.x * d0.z + xv.y * d1.z + xv.z * d2.z + xv.w * d3.z;
        acc[R].w += xv.x * d0.w + xv.y * d1.w + xv.z * d2.w + xv.w * d3.w;
    }
}

// ---------------------------------------------------------------------------
// One block = sibling leaf PAIR, full C. 512 blocks x 512 threads, 2/CU,
// 16 waves/CU (R11 residency). Stream bodies verbatim from the R11 winner;
// demand 459 MB (R12 proved further cuts don't pay — HBM-bound now).
// Block owns both leaves' full logits -> softmax fused in-block; out written
// directly. Only the tiny reg partial needs a second kernel.
// Thread tile: 16 f x 4 c; lanes 0..15 span a contiguous 256B row segment.
// ---------------------------------------------------------------------------
__global__ __launch_bounds__(512, 2) void k_fused(const float* __restrict__ x,
                                                  const float* __restrict__ deltas,
                                                  const float* __restrict__ heights,
                                                  float* __restrict__ out,
                                                  float* __restrict__ ws)
{
    __shared__ float red[8 * 132];   // [wave][r*64 + c], stride 132 pad
    __shared__ float rr[8];

    const int tid = threadIdx.x;
    const int bid = blockIdx.x;
    // XCD k owns pairs [64k,64k+64) = leaves [128k,128k+128)
    const int k  = bid & 7;
    const int t  = bid >> 3;            // 0..63
    const int p  = (k << 6) | t;        // pair 0..511
    const int l0 = 2 * p;               // first leaf of pair
    const int fg = tid >> 4;            // 0..31 (16 f each)
    const int cq = tid & 15;            // c-quad (full 64 c)

    // x fragments: 2 leaves x 16 f = 8 float4
    float4 xr[2][4];
#pragma unroll
    for (int r = 0; r < 2; ++r)
#pragma unroll
        for (int j = 0; j < 4; ++j)
            xr[r][j] = *(const float4*)(x + (size_t)(l0 + r) * FDIM + fg * 16 + 4 * j);

    float4 acc[2];
    acc[0] = make_float4(0.f, 0.f, 0.f, 0.f);
    acc[1] = make_float4(0.f, 0.f, 0.f, 0.f);
    float rsum = 0.f;
    const size_t toff = (size_t)(fg * 16) * CDIM + cq * 4;

    // ---- shared ancestors root -> d4 (branchy runtime loop = hoist stopper)
#pragma unroll
    for (int d = 0; d < 5; ++d) {
        const int shift = 2 * (5 - d);
        const int start = ((1 << (2 * d)) - 1) / 3;   // 0,1,5,21,85
        const int node  = start + (l0 >> shift);
        const float* dbase = deltas + (size_t)node * MAT + toff;
        const bool doReg = (l0 & ((1 << shift) - 1)) == 0;
        if (d == 0) {
            if (doReg) stream2<2>(dbase, xr, acc, rsum, 1.f);
            else       stream2<0>(dbase, xr, acc, rsum, 0.f);
        } else {
            if (doReg) {
                const int par = (node - 1) >> 2;
                const float s = 1.f / fmaxf(fabsf(heights[node] - heights[par]), 1e-7f);
                stream2<1>(dbase, xr, acc, rsum, s);
            } else {
                stream2<0>(dbase, xr, acc, rsum, 0.f);
            }
        }
    }

    // ---- the two leaf slabs; sched_barrier bounds load hoisting
    {
        const int n5 = 341 + l0;
        const float hp = heights[85 + (l0 >> 2)];
        const float sA = 1.f / fmaxf(fabsf(heights[n5]     - hp), 1e-7f);
        stream1<0>(deltas + (size_t)n5 * MAT + toff, xr, acc, rsum, sA);
        __builtin_amdgcn_sched_barrier(0);
        const float sB = 1.f / fmaxf(fabsf(heights[n5 + 1] - hp), 1e-7f);
        stream1<1>(deltas + (size_t)(n5 + 1) * MAT + toff, xr, acc, rsum, sB);
    }

    // ---- reduce over the 4 fg per wave (fg spans lane bits 4,5)
#pragma unroll
    for (int r = 0; r < 2; ++r) {
        acc[r].x += __shfl_xor(acc[r].x, 16, 64);  acc[r].x += __shfl_xor(acc[r].x, 32, 64);
        acc[r].y += __shfl_xor(acc[r].y, 16, 64);  acc[r].y += __shfl_xor(acc[r].y, 32, 64);
        acc[r].z += __shfl_xor(acc[r].z, 16, 64);  acc[r].z += __shfl_xor(acc[r].z, 32, 64);
        acc[r].w += __shfl_xor(acc[r].w, 16, 64);  acc[r].w += __shfl_xor(acc[r].w, 32, 64);
    }

    const int w = tid >> 6, lane = tid & 63;
    if (lane < 16) {   // lane == cq
#pragma unroll
        for (int r = 0; r < 2; ++r)
            *(float4*)(red + w * 132 + r * 64 + cq * 4) = acc[r];
    }

    // ---- reg partial: full-wave butterfly -> LDS
#pragma unroll
    for (int off = 1; off < 64; off <<= 1) rsum += __shfl_xor(rsum, off, 64);
    if (lane == 0) rr[w] = rsum;
    __syncthreads();

    // ---- fused softmax: waves 0-1, one wave per leaf row (c = lane)
    if (tid < 128) {
        const int r = tid >> 6;   // leaf row 0/1
        const int c = tid & 63;
        float v = 0.f;
#pragma unroll
        for (int w2 = 0; w2 < 8; ++w2) v += red[w2 * 132 + r * 64 + c];
        float m = v;
#pragma unroll
        for (int off = 32; off > 0; off >>= 1) m = fmaxf(m, __shfl_xor(m, off, 64));
        const float e = expf(v - m);
        float s2 = e;
#pragma unroll
        for (int off = 32; off > 0; off >>= 1) s2 += __shfl_xor(s2, off, 64);
        out[(size_t)(l0 + r) * CDIM + c] = e / s2;
    } else if (tid == 128) {
        float v = 0.f;
#pragma unroll
        for (int w2 = 0; w2 < 8; ++w2) v += rr[w2];
        ws[bid] = v;
    }
}

// ---------------------------------------------------------------------------
// Sum the 512 reg partials -> out[OUT_LOGITS]
// ---------------------------------------------------------------------------
__global__ __launch_bounds__(256) void k_regsum(const float* __restrict__ ws,
                                                float* __restrict__ out)
{
    __shared__ float r[4];
    const int tid = threadIdx.x;
    float v = ws[tid] + ws[256 + tid];
#pragma unroll
    for (int off = 1; off < 64; off <<= 1) v += __shfl_xor(v, off, 64);
    if ((tid & 63) == 0) r[tid >> 6] = v;
    __syncthreads();
    if (tid == 0) out[OUT_LOGITS] = r[0] + r[1] + r[2] + r[3];
}

extern "C" void kernel_launch(void* const* d_in, const int* in_sizes, int n_in,
                              void* d_out, int out_size, void* d_ws, size_t ws_size,
                              hipStream_t stream)
{
    const float* x       = (const float*)d_in[0];
    const float* deltas  = (const float*)d_in[1];
    const float* heights = (const float*)d_in[2];
    float* out = (float*)d_out;
    float* ws  = (float*)d_ws;

    k_fused<<<512, 512, 0, stream>>>(x, deltas, heights, out, ws);
    k_regsum<<<1, 256, 0, stream>>>(ws, out);
}

// Round 14
// 38.008 us; speedup vs baseline: 1.0831x; 1.0831x over previous
//
#include <hip/hip_runtime.h>

#define FDIM 512
#define CDIM 64
#define NLEAF 1024
#define MAT (FDIM * CDIM)          /* 32768 floats per node */
#define OUT_LOGITS (NLEAF * CDIM)  /* 65536 */
#define WS_REG (NLEAF * CDIM)      /* float offset of reg partials in ws */

__device__ __forceinline__ float abs4(const float4 v) {
    return fabsf(v.x) + fabsf(v.y) + fabsf(v.z) + fabsf(v.w);
}
__device__ __forceinline__ float sq4(const float4 v) {
    return v.x * v.x + v.y * v.y + v.z * v.z + v.w * v.w;
}

// Shared-ancestor stream: this thread's 16f x 4c (c-half) tile of one node,
// 4 bursts x 4-deep (R3-proven shape); FMA into BOTH leaves' accs.
// MODE: 0 = none, 1 = L1*scale, 2 = squared (root)   [verbatim R11 winner]
template<int MODE>
__device__ __forceinline__ void stream2(const float* __restrict__ dbase,
                                        const float4 xr[2][4],
                                        float4* __restrict__ acc,
                                        float& rsum, float s)
{
#pragma unroll
    for (int h = 0; h < 4; ++h) {
        const float* q = dbase + (size_t)(4 * h) * CDIM;
        const float4 d0 = *(const float4*)(q);
        const float4 d1 = *(const float4*)(q + CDIM);
        const float4 d2 = *(const float4*)(q + 2 * CDIM);
        const float4 d3 = *(const float4*)(q + 3 * CDIM);
        if (MODE == 1) rsum = fmaf(abs4(d0) + abs4(d1) + abs4(d2) + abs4(d3), s, rsum);
        if (MODE == 2) rsum += sq4(d0) + sq4(d1) + sq4(d2) + sq4(d3);
#pragma unroll
        for (int r = 0; r < 2; ++r) {
            const float4 xv = xr[r][h];
            acc[r].x += xv.x * d0.x + xv.y * d1.x + xv.z * d2.x + xv.w * d3.x;
            acc[r].y += xv.x * d0.y + xv.y * d1.y + xv.z * d2.y + xv.w * d3.y;
            acc[r].z += xv.x * d0.z + xv.y * d1.z + xv.z * d2.z + xv.w * d3.z;
            acc[r].w += xv.x * d0.w + xv.y * d1.w + xv.z * d2.w + xv.w * d3.w;
        }
    }
}

// Leaf stream: same shape, FMA into acc[R] only; always reg-owner. [R11]
template<int R>
__device__ __forceinline__ void stream1(const float* __restrict__ dbase,
                                        const float4 xr[2][4],
                                        float4* __restrict__ acc,
                                        float& rsum, float s)
{
#pragma unroll
    for (int h = 0; h < 4; ++h) {
        const float* q = dbase + (size_t)(4 * h) * CDIM;
        const float4 d0 = *(const float4*)(q);
        const float4 d1 = *(const float4*)(q + CDIM);
        const float4 d2 = *(const float4*)(q + 2 * CDIM);
        const float4 d3 = *(const float4*)(q + 3 * CDIM);
        rsum = fmaf(abs4(d0) + abs4(d1) + abs4(d2) + abs4(d3), s, rsum);
        const float4 xv = xr[R][h];
        acc[R].x += xv.x * d0.x + xv.y * d1.x + xv.z * d2.x + xv.w * d3.x;
        acc[R].y += xv.x * d0.y + xv.y * d1.y + xv.z * d2.y + xv.w * d3.y;
        acc[R].z += xv.x * d0.z + xv.y * d1.z + xv.z * d2.z + xv.w * d3.z;
        acc[R].w += xv.x * d0.w + xv.y * d1.w + xv.z * d2.w + xv.w * d3.w;
    }
}

// ---------------------------------------------------------------------------
// One block = (sibling leaf PAIR) x (c-half). 1024 blocks x 256 threads,
// 4 blocks/CU, 16 waves/CU. __launch_bounds__(256,2) -> ~128 VGPR budget
// (the (256,4) bound capped at 64 and spilled 80 MB in R10). Demand: 5
// shared ancestors streamed once per PAIR -> 459 MB L2-side (R12 proved
// deeper cuts don't pay; HBM unique-byte stream is the binding floor).
// BYTE-IDENTICAL to the round-11 winner (39.2 us).
// ---------------------------------------------------------------------------
__global__ __launch_bounds__(256, 2) void k_fused(const float* __restrict__ x,
                                                  const float* __restrict__ deltas,
                                                  const float* __restrict__ heights,
                                                  float* __restrict__ ws)
{
    __shared__ float red[4 * 64];   // [wave][r*32 + cq*4 + comp]
    __shared__ float rr[4];

    const int tid = threadIdx.x;
    const int bid = blockIdx.x;
    // XCD k owns pairs [64k,64k+64) = leaves [128k,128k+128); both c-halves
    // of a pair are dispatch-adjacent on the same XCD.
    const int k  = bid & 7;
    const int t  = bid >> 3;            // 0..127
    const int p  = (k << 6) | (t >> 1); // pair 0..511
    const int ch = t & 1;               // c-half
    const int l0 = 2 * p;               // first leaf of pair
    const int fg = tid >> 3;            // 0..31 (16 f each)
    const int cq = tid & 7;             // c-quad within half
    const int c0 = ch * 32 + cq * 4;

    // x fragments: 2 leaves x 16 f = 8 float4
    float4 xr[2][4];
#pragma unroll
    for (int r = 0; r < 2; ++r)
#pragma unroll
        for (int j = 0; j < 4; ++j)
            xr[r][j] = *(const float4*)(x + (size_t)(l0 + r) * FDIM + fg * 16 + 4 * j);

    float4 acc[2];
    acc[0] = make_float4(0.f, 0.f, 0.f, 0.f);
    acc[1] = make_float4(0.f, 0.f, 0.f, 0.f);
    float rsum = 0.f;
    const size_t toff = (size_t)(fg * 16) * CDIM + c0;

    // ---- shared ancestors root -> depth 4 (branchy runtime loop)
#pragma unroll
    for (int d = 0; d < 5; ++d) {
        const int shift = 2 * (5 - d);
        const int start = ((1 << (2 * d)) - 1) / 3;   // 0,1,5,21,85
        const int node  = start + (l0 >> shift);
        const float* dbase = deltas + (size_t)node * MAT + toff;
        const bool doReg = (l0 & ((1 << shift) - 1)) == 0;
        if (d == 0) {
            if (doReg) stream2<2>(dbase, xr, acc, rsum, 1.f);
            else       stream2<0>(dbase, xr, acc, rsum, 0.f);
        } else {
            if (doReg) {
                const int par = (node - 1) >> 2;
                const float s = 1.f / fmaxf(fabsf(heights[node] - heights[par]), 1e-7f);
                stream2<1>(dbase, xr, acc, rsum, s);
            } else {
                stream2<0>(dbase, xr, acc, rsum, 0.f);
            }
        }
    }

    // ---- the two leaf slabs (c-half each); barrier bounds load hoisting
    {
        const int n5 = 341 + l0;
        const float hp = heights[85 + (l0 >> 2)];
        const float sA = 1.f / fmaxf(fabsf(heights[n5]     - hp), 1e-7f);
        stream1<0>(deltas + (size_t)n5 * MAT + toff, xr, acc, rsum, sA);
        __builtin_amdgcn_sched_barrier(0);
        const float sB = 1.f / fmaxf(fabsf(heights[n5 + 1] - hp), 1e-7f);
        stream1<1>(deltas + (size_t)(n5 + 1) * MAT + toff, xr, acc, rsum, sB);
    }

    // ---- reduce over fg within wave (fg spans lane bits 3,4,5)
#pragma unroll
    for (int r = 0; r < 2; ++r) {
        acc[r].x += __shfl_xor(acc[r].x, 8, 64); acc[r].x += __shfl_xor(acc[r].x, 16, 64); acc[r].x += __shfl_xor(acc[r].x, 32, 64);
        acc[r].y += __shfl_xor(acc[r].y, 8, 64); acc[r].y += __shfl_xor(acc[r].y, 16, 64); acc[r].y += __shfl_xor(acc[r].y, 32, 64);
        acc[r].z += __shfl_xor(acc[r].z, 8, 64); acc[r].z += __shfl_xor(acc[r].z, 16, 64); acc[r].z += __shfl_xor(acc[r].z, 32, 64);
        acc[r].w += __shfl_xor(acc[r].w, 8, 64); acc[r].w += __shfl_xor(acc[r].w, 16, 64); acc[r].w += __shfl_xor(acc[r].w, 32, 64);
    }

    const int w = tid >> 6, lane = tid & 63;
    if (lane < 8) {   // lane == cq
#pragma unroll
        for (int r = 0; r < 2; ++r)
            *(float4*)(red + w * 64 + r * 32 + cq * 4) = acc[r];
    }

    // ---- reg partial: full-wave butterfly -> LDS
#pragma unroll
    for (int off = 1; off < 64; off <<= 1) rsum += __shfl_xor(rsum, off, 64);
    if (lane == 0) rr[w] = rsum;
    __syncthreads();

    // ---- write the 64 complete logits this block owns (f fully reduced)
    if (tid < 64) {
        const int r = tid >> 5, cc = tid & 31;
        const float v = red[0 * 64 + r * 32 + cc] + red[1 * 64 + r * 32 + cc]
                      + red[2 * 64 + r * 32 + cc] + red[3 * 64 + r * 32 + cc];
        ws[(size_t)(l0 + r) * CDIM + ch * 32 + cc] = v;
    }
    if (tid == 64)
        ws[WS_REG + bid] = rr[0] + rr[1] + rr[2] + rr[3];
}

// ---------------------------------------------------------------------------
// Finish: softmax per leaf row (logits complete in ws); block 255 also sums
// the 1024 reg partials -> out[OUT_LOGITS]. 256 blocks x 256 threads.
// ---------------------------------------------------------------------------
__global__ __launch_bounds__(256) void k_finish(const float* __restrict__ ws,
                                                float* __restrict__ out)
{
    const int tid = threadIdx.x;
    const int l = blockIdx.x * 4 + (tid >> 6);
    const int c = tid & 63;
    const float v = ws[(size_t)l * CDIM + c];
    float m = v;
#pragma unroll
    for (int off = 32; off > 0; off >>= 1) m = fmaxf(m, __shfl_xor(m, off, 64));
    const float e = expf(v - m);
    float s = e;
#pragma unroll
    for (int off = 32; off > 0; off >>= 1) s += __shfl_xor(s, off, 64);
    out[(size_t)l * CDIM + c] = e / s;

    // ---- merged regsum (block 255 only): 1024 partials -> scalar
    if (blockIdx.x == 255) {
        __shared__ float r[4];
        const float* q = ws + WS_REG;
        float rv = q[tid] + q[256 + tid] + q[512 + tid] + q[768 + tid];
#pragma unroll
        for (int off = 1; off < 64; off <<= 1) rv += __shfl_xor(rv, off, 64);
        if ((tid & 63) == 0) r[tid >> 6] = rv;
        __syncthreads();
        if (tid == 0) out[OUT_LOGITS] = r[0] + r[1] + r[2] + r[3];
    }
}

extern "C" void kernel_launch(void* const* d_in, const int* in_sizes, int n_in,
                              void* d_out, int out_size, void* d_ws, size_t ws_size,
                              hipStream_t stream)
{
    const float* x       = (const float*)d_in[0];
    const float* deltas  = (const float*)d_in[1];
    const float* heights = (const float*)d_in[2];
    float* out = (float*)d_out;
    float* ws  = (float*)d_ws;

    k_fused<<<NLEAF, 256, 0, stream>>>(x, deltas, heights, ws);
    k_finish<<<256, 256, 0, stream>>>(ws, out);
}